// Round 6
// baseline (292.723 us; speedup 1.0000x reference)
//
#include <hip/hip_runtime.h>
#include <hip/hip_bf16.h>

// Problem constants (from reference)
constexpr int BATCH = 4096;   // N
constexpr int NCLS  = 751;    // classes
constexpr int FDIM  = 2048;   // D
constexpr int TILE  = 128;    // C-tile (square)
constexpr int BK    = 32;     // K-step (one mfma_16x16x32 per step)
constexpr int NIT   = FDIM / BK;  // 64 K-iterations
constexpr float MARGIN = 0.5f;

constexpr int NTILE = BATCH / TILE;               // 32
constexpr int NOFF  = NTILE * (NTILE - 1) / 2;    // 496 strictly-lower tiles
constexpr int NWORK = NOFF + NTILE;               // 528 (diag last = light tail)
constexpr int NWORKERS = 1024;                    // 4 blocks/CU, ticket queue

constexpr int NCONV = 512;                        // prep: convert blocks (8 rows)
constexpr int NXENT = 512;                        // prep: xent blocks (8 rows)

typedef __attribute__((ext_vector_type(8))) short bf16x8;  // 8 bf16 = 4 VGPRs
typedef __attribute__((ext_vector_type(4))) float f32x4;

// ---------------- helpers ----------------
__device__ __forceinline__ float wave_sum(float v) {
#pragma unroll
  for (int m = 32; m >= 1; m >>= 1) v += __shfl_xor(v, m, 64);
  return v;
}

__device__ __forceinline__ unsigned short bf_bits(float x) {
  unsigned u = __float_as_uint(x);
  u += 0x7FFFu + ((u >> 16) & 1u);   // RNE to bf16
  return (unsigned short)(u >> 16);
}

__device__ __forceinline__ void gld_lds16(const void* g, void* l) {
  __builtin_amdgcn_global_load_lds(
      (const __attribute__((address_space(1))) void*)g,
      (__attribute__((address_space(3))) void*)l, 16, 0, 0);
}

// ---------------- kernel 1 (prep): convert + xent + init (R4, passed) -------
__global__ __launch_bounds__(256) void prep_kernel(
    const float* __restrict__ feat, const float* __restrict__ logits,
    const int* __restrict__ tgt, unsigned short* __restrict__ fb,
    float* __restrict__ sq, int* __restrict__ an, int* __restrict__ ap,
    float* __restrict__ xloss, int* __restrict__ ctrs) {
  const int b = blockIdx.x;
  const int tid = threadIdx.x;
  const int wave = tid >> 6, lane = tid & 63;

  if (b == 0 && tid == 0) { ctrs[0] = 0; ctrs[1] = 0; }  // ticket, done

  if (b < NCONV) {
    if (tid < 8) {
      an[b * 8 + tid] = 0x7F000000;   // big positive float bits (min identity)
      ap[b * 8 + tid] = 0;            // 0.0f bits (max identity)
    }
#pragma unroll
    for (int rr = 0; rr < 2; ++rr) {
      const int row = b * 8 + wave * 2 + rr;
      const float4* src = (const float4*)(feat + (size_t)row * FDIM);
      ushort4* dst = (ushort4*)(fb + (size_t)row * FDIM);
      float s = 0.f;
#pragma unroll
      for (int it = 0; it < 8; ++it) {     // 512 float4 per row / 64 lanes
        const int idx = it * 64 + lane;
        float4 v = src[idx];
        s += v.x * v.x + v.y * v.y + v.z * v.z + v.w * v.w;
        ushort4 o;
        o.x = bf_bits(v.x); o.y = bf_bits(v.y);
        o.z = bf_bits(v.z); o.w = bf_bits(v.w);
        dst[idx] = o;
      }
      s = wave_sum(s);
      if (lane == 0) sq[row] = s;
    }
  } else {
    const int r0 = (b - NCONV) * 8;
#pragma unroll
    for (int rr = 0; rr < 2; ++rr) {
      const int row = r0 + rr * 4 + wave;
      const float* lg = logits + (size_t)row * NCLS;
      float m = -1e30f;
      for (int j = lane; j < NCLS; j += 64) m = fmaxf(m, lg[j]);
#pragma unroll
      for (int s = 32; s >= 1; s >>= 1) m = fmaxf(m, __shfl_xor(m, s, 64));
      float se = 0.f;
      for (int j = lane; j < NCLS; j += 64) se += __expf(lg[j] - m);
      se = wave_sum(se);
      if (lane == 0) xloss[row] = -(lg[tgt[row]] - m - logf(se));
    }
  }
}

// ---------------- kernel 2 (mega): ticket-queue Gram + mining + final -------
// 1024 workers x 256 thr (4 waves, 2x2, 4x4 frags). Conflict-free LDS layout:
// tile stored [quad][row][8] (quad = K-chunk of 8 bf16). Fragment read for
// (row, quad) = 16B chunk (quad*128 + row) -> 16 consecutive chunks per
// quad-group of lanes = every bank exactly 8x per wave read (structural
// minimum, 0 conflicts), vs row-major's 2x serialization on banks {0-3,16-19}.
// Staging permutation: thread t fetches global (row = t&127, kchunk = t>>7)
// so the fixed global_load_lds write (chunk t, then 256+t) lands correctly.
__global__ __launch_bounds__(256, 2) void mega_kernel(
    const unsigned short* __restrict__ fb, const float* __restrict__ sq,
    int* __restrict__ an, int* __restrict__ ap,
    const float* __restrict__ xloss, float* __restrict__ out,
    int* __restrict__ ctrs) {
  __shared__ __align__(16) unsigned short As[2][TILE * BK];  // 2 x 8 KB
  __shared__ __align__(16) unsigned short Bs[2][TILE * BK];  // 2 x 8 KB
  __shared__ int s_tile;
  __shared__ int s_last;

  const int tid = threadIdx.x;
  const int wave = tid >> 6, lane = tid & 63;
  const int wm = wave >> 1, wn = wave & 1;        // 2x2 wave grid
  const int quad = lane >> 4, lr = lane & 15;

  // staging map (conflict-free layout): thread t -> global (row, kq)
  const int srow = tid & 127;
  const int skq  = tid >> 7;               // 0 or 1
  const int lo1 = tid * 8;                 // LDS chunk t   (elements)
  const int lo2 = (256 + tid) * 8;         // LDS chunk 256+t

  for (;;) {
    if (tid == 0) s_tile = atomicAdd(&ctrs[0], 1);
    __syncthreads();
    const int t = s_tile;
    if (t >= NWORK) break;

    int bi, bj;
    bool diag;
    if (t < NOFF) {   // strictly-lower triangle: t = bi*(bi-1)/2 + bj, bj < bi
      bi = (int)((1.f + sqrtf(8.f * (float)t + 1.f)) * 0.5f);
      while (bi * (bi - 1) / 2 > t) --bi;
      while ((bi + 1) * bi / 2 <= t) ++bi;
      bj = t - bi * (bi - 1) / 2;
      diag = false;
    } else {
      bi = bj = t - NOFF;
      diag = true;
    }
    const int i0 = bi * TILE, j0 = bj * TILE;

    f32x4 acc[4][4];
    const f32x4 zero = {0.f, 0.f, 0.f, 0.f};
#pragma unroll
    for (int mi = 0; mi < 4; ++mi)
#pragma unroll
      for (int ni = 0; ni < 4; ++ni) acc[mi][ni] = zero;

    const unsigned short* gA = fb + (size_t)(i0 + srow) * FDIM + skq * 8;
    const unsigned short* gB = fb + (size_t)(j0 + srow) * FDIM + skq * 8;

    // prefetch iteration 0 into buffer 0
    gld_lds16(gA, &As[0][lo1]);
    gld_lds16(gA + 16, &As[0][lo2]);       // k-chunks 2,3 (cols 16..31)
    if (!diag) {
      gld_lds16(gB, &Bs[0][lo1]);
      gld_lds16(gB + 16, &Bs[0][lo2]);
    }

    for (int it = 0; it < NIT; ++it) {
      const int cur = it & 1;
      __syncthreads();             // drains vmcnt -> buffer `cur` visible
      if (it + 1 < NIT) {
        const int nk = (it + 1) * BK;
        const int nb = cur ^ 1;
        gld_lds16(gA + nk, &As[nb][lo1]);
        gld_lds16(gA + nk + 16, &As[nb][lo2]);
        if (!diag) {
          gld_lds16(gB + nk, &Bs[nb][lo1]);
          gld_lds16(gB + nk + 16, &Bs[nb][lo2]);
        }
      }
      const unsigned short* Asb = As[cur];
      const unsigned short* Bsb = diag ? As[cur] : Bs[cur];

      bf16x8 a[4], bfr[4];
#pragma unroll
      for (int mi = 0; mi < 4; ++mi)
        a[mi] = *(const bf16x8*)&Asb[(quad * 128 + wm * 64 + mi * 16 + lr) * 8];
#pragma unroll
      for (int ni = 0; ni < 4; ++ni)
        bfr[ni] = *(const bf16x8*)&Bsb[(quad * 128 + wn * 64 + ni * 16 + lr) * 8];
#pragma unroll
      for (int mi = 0; mi < 4; ++mi)
#pragma unroll
        for (int ni = 0; ni < 4; ++ni)
          acc[mi][ni] = __builtin_amdgcn_mfma_f32_16x16x32_bf16(
              a[mi], bfr[ni], acc[mi][ni], 0, 0, 0);
    }

    // ---- epilogue: D layout col = lane&15 (j), row = quad*4 + reg (i) ----
    float sqj[4];
#pragma unroll
    for (int ni = 0; ni < 4; ++ni) sqj[ni] = sq[j0 + wn * 64 + ni * 16 + lr];

    if (diag) {
      float rmin[4][4], rmax[4][4];
#pragma unroll
      for (int mi = 0; mi < 4; ++mi)
#pragma unroll
        for (int rg = 0; rg < 4; ++rg) { rmin[mi][rg] = 1e30f; rmax[mi][rg] = 0.f; }
#pragma unroll
      for (int mi = 0; mi < 4; ++mi) {
#pragma unroll
        for (int rg = 0; rg < 4; ++rg) {
          const int i = i0 + wm * 64 + mi * 16 + quad * 4 + rg;
          const float si_ = sq[i];
          const int gi = i >> 2;       // targets = idx // 4
#pragma unroll
          for (int ni = 0; ni < 4; ++ni) {
            const int j = j0 + wn * 64 + ni * 16 + lr;
            const float d2 = si_ + sqj[ni] - 2.f * acc[mi][ni][rg];
            const float dist = sqrtf(fmaxf(d2, 1e-12f));
            if ((j >> 2) == gi) rmax[mi][rg] = fmaxf(rmax[mi][rg], dist);
            else                rmin[mi][rg] = fminf(rmin[mi][rg], dist);
          }
        }
      }
#pragma unroll
      for (int m = 1; m < 16; m <<= 1)
#pragma unroll
        for (int mi = 0; mi < 4; ++mi)
#pragma unroll
          for (int rg = 0; rg < 4; ++rg) {
            rmin[mi][rg] = fminf(rmin[mi][rg], __shfl_xor(rmin[mi][rg], m, 64));
            rmax[mi][rg] = fmaxf(rmax[mi][rg], __shfl_xor(rmax[mi][rg], m, 64));
          }
      if (lr == 0) {
#pragma unroll
        for (int mi = 0; mi < 4; ++mi)
#pragma unroll
          for (int rg = 0; rg < 4; ++rg) {
            const int i = i0 + wm * 64 + mi * 16 + quad * 4 + rg;
            atomicMin(&an[i], __float_as_int(rmin[mi][rg]));
            atomicMax(&ap[i], __float_as_int(rmax[mi][rg]));
          }
      }
    } else {
      float rmin[4][4];
      float cmin[4] = {1e30f, 1e30f, 1e30f, 1e30f};
#pragma unroll
      for (int mi = 0; mi < 4; ++mi)
#pragma unroll
        for (int rg = 0; rg < 4; ++rg) rmin[mi][rg] = 1e30f;
#pragma unroll
      for (int mi = 0; mi < 4; ++mi) {
#pragma unroll
        for (int rg = 0; rg < 4; ++rg) {
          const float si_ = sq[i0 + wm * 64 + mi * 16 + quad * 4 + rg];
#pragma unroll
          for (int ni = 0; ni < 4; ++ni) {
            const float d2 = si_ + sqj[ni] - 2.f * acc[mi][ni][rg];
            const float dist = sqrtf(fmaxf(d2, 1e-12f));
            rmin[mi][rg] = fminf(rmin[mi][rg], dist);
            cmin[ni] = fminf(cmin[ni], dist);
          }
        }
      }
      // rows: reduce across lr lanes (masks 1,2,4,8)
#pragma unroll
      for (int m = 1; m < 16; m <<= 1)
#pragma unroll
        for (int mi = 0; mi < 4; ++mi)
#pragma unroll
          for (int rg = 0; rg < 4; ++rg)
            rmin[mi][rg] = fminf(rmin[mi][rg], __shfl_xor(rmin[mi][rg], m, 64));
      if (lr == 0) {
#pragma unroll
        for (int mi = 0; mi < 4; ++mi)
#pragma unroll
          for (int rg = 0; rg < 4; ++rg) {
            const int i = i0 + wm * 64 + mi * 16 + quad * 4 + rg;
            atomicMin(&an[i], __float_as_int(rmin[mi][rg]));
          }
      }
      // cols: reduce across quad groups (masks 16,32); symmetry -> an[j]
#pragma unroll
      for (int ni = 0; ni < 4; ++ni) {
        cmin[ni] = fminf(cmin[ni], __shfl_xor(cmin[ni], 16, 64));
        cmin[ni] = fminf(cmin[ni], __shfl_xor(cmin[ni], 32, 64));
      }
      if (quad == 0) {
#pragma unroll
        for (int ni = 0; ni < 4; ++ni) {
          const int j = j0 + wn * 64 + ni * 16 + lr;
          atomicMin(&an[j], __float_as_int(cmin[ni]));
        }
      }
    }
  }

  // ---------------- done protocol + fused final reduction (R4, passed) ------
  __threadfence();                 // publish this block's atomics (release)
  __syncthreads();
  if (tid == 0) s_last = (atomicAdd(&ctrs[1], 1) == NWORKERS - 1) ? 1 : 0;
  __syncthreads();
  if (s_last) {
    __threadfence();               // acquire
    float st = 0.f, sx = 0.f;
    for (int i = tid; i < BATCH; i += 256) {
      const float a = __int_as_float(__hip_atomic_load(
          &ap[i], __ATOMIC_RELAXED, __HIP_MEMORY_SCOPE_AGENT));
      const float bn = __int_as_float(__hip_atomic_load(
          &an[i], __ATOMIC_RELAXED, __HIP_MEMORY_SCOPE_AGENT));
      st += fmaxf(a - bn + MARGIN, 0.f);
      sx += xloss[i];
    }
    st = wave_sum(st);
    sx = wave_sum(sx);
    __shared__ float s1[4], s2[4];
    if (lane == 0) { s1[wave] = st; s2[wave] = sx; }
    __syncthreads();
    if (tid == 0) {
      const float trip = (s1[0] + s1[1] + s1[2] + s1[3]) / (float)BATCH;
      const float xent = (s2[0] + s2[1] + s2[2] + s2[3]) / (float)BATCH;
      out[0] = xent + trip;  // ALPHA=BETA=1
    }
  }
}

// ---------------- launch ----------------
extern "C" void kernel_launch(void* const* d_in, const int* in_sizes, int n_in,
                              void* d_out, int out_size, void* d_ws, size_t ws_size,
                              hipStream_t stream) {
  const float* logits = (const float*)d_in[0];
  const float* feat   = (const float*)d_in[1];
  const int*   tgt    = (const int*)d_in[2];
  float* out = (float*)d_out;

  // ws layout: bf16 feat copy (16 MB) | sq | an | ap | xloss | ctrs
  char* ws = (char*)d_ws;
  unsigned short* fb = (unsigned short*)ws;
  size_t off = (size_t)BATCH * FDIM * sizeof(unsigned short);
  float* sq    = (float*)(ws + off);  off += BATCH * sizeof(float);
  int*   an    = (int*)(ws + off);    off += BATCH * sizeof(int);
  int*   ap    = (int*)(ws + off);    off += BATCH * sizeof(int);
  float* xloss = (float*)(ws + off);  off += BATCH * sizeof(float);
  int*   ctrs  = (int*)(ws + off);

  prep_kernel<<<NCONV + NXENT, 256, 0, stream>>>(feat, logits, tgt, fb, sq, an,
                                                 ap, xloss, ctrs);
  mega_kernel<<<NWORKERS, 256, 0, stream>>>(fb, sq, an, ap, xloss, out, ctrs);
}

// Round 7
// 262.681 us; speedup vs baseline: 1.1144x; 1.1144x over previous
//
#include <hip/hip_runtime.h>
#include <hip/hip_bf16.h>

// Problem constants (from reference)
constexpr int BATCH = 4096;   // N
constexpr int NCLS  = 751;    // classes
constexpr int FDIM  = 2048;   // D
constexpr int TM    = 128;    // tile rows
constexpr int TN    = 64;     // tile cols
constexpr int BK    = 32;     // K-step (one mfma_16x16x32 per step)
constexpr int NIT   = FDIM / BK;  // 64 K-iterations
constexpr float MARGIN = 0.5f;

// triangle at 128x64 granularity: unit (rb, cb), rb in [0,32), cb <= 2rb+1.
// u = rb*(rb+1) + cb.  total = 32*33 = 1056.
constexpr int NU    = 1056;           // gemm units
constexpr int NXB   = BATCH / 4;      // 1024 xent blocks (4 rows each)
constexpr int NTOT  = NU + NXB;       // 2080 blocks in mega grid

typedef __attribute__((ext_vector_type(8))) short bf16x8;  // 8 bf16 = 4 VGPRs
typedef __attribute__((ext_vector_type(4))) float f32x4;

// ---------------- helpers ----------------
__device__ __forceinline__ float wave_sum(float v) {
#pragma unroll
  for (int m = 32; m >= 1; m >>= 1) v += __shfl_xor(v, m, 64);
  return v;
}

__device__ __forceinline__ unsigned short bf_bits(float x) {
  unsigned u = __float_as_uint(x);
  u += 0x7FFFu + ((u >> 16) & 1u);   // RNE to bf16
  return (unsigned short)(u >> 16);
}

__device__ __forceinline__ void gld_lds16(const void* g, void* l) {
  __builtin_amdgcn_global_load_lds(
      (const __attribute__((address_space(1))) void*)g,
      (__attribute__((address_space(3))) void*)l, 16, 0, 0);
}

// ---------------- kernel 1 (prep): fp32->bf16 convert + sumsq + init --------
__global__ __launch_bounds__(256) void prep_kernel(
    const float* __restrict__ feat, unsigned short* __restrict__ fb,
    float* __restrict__ sq, int* __restrict__ an, int* __restrict__ ap,
    int* __restrict__ ctrs) {
  const int b = blockIdx.x;
  const int tid = threadIdx.x;
  const int wave = tid >> 6, lane = tid & 63;

  if (b == 0 && tid == 0) { ctrs[0] = 0; ctrs[1] = 0; }
  if (tid < 8) {
    an[b * 8 + tid] = 0x7F000000;   // big positive float bits (min identity)
    ap[b * 8 + tid] = 0;            // 0.0f bits (max identity; dist >= 0)
  }
#pragma unroll
  for (int rr = 0; rr < 2; ++rr) {
    const int row = b * 8 + wave * 2 + rr;
    const float4* src = (const float4*)(feat + (size_t)row * FDIM);
    ushort4* dst = (ushort4*)(fb + (size_t)row * FDIM);
    float s = 0.f;
#pragma unroll
    for (int it = 0; it < 8; ++it) {     // 512 float4 per row / 64 lanes
      const int idx = it * 64 + lane;
      float4 v = src[idx];
      s += v.x * v.x + v.y * v.y + v.z * v.z + v.w * v.w;
      ushort4 o;
      o.x = bf_bits(v.x); o.y = bf_bits(v.y);
      o.z = bf_bits(v.z); o.w = bf_bits(v.w);
      dst[idx] = o;
    }
    s = wave_sum(s);
    if (lane == 0) sq[row] = s;
  }
}

// ---------------- kernel 2 (mega): 128x64-tile symmetric Gram + mining -------
// 2080 blocks x 128 thr (2 waves). Blocks [0,NU): gemm unit; [NU,NTOT): xent
// (4 rows). 12 KB LDS, R1's proven coalesced staging (16x64B segments/wave),
// row-major LDS (2-way bank aliasing = free, m136). 8 blocks/CU resident ->
// 8 independent barrier domains hide the staging latency that bound R1/R3.
// Dynamically-last block does the final loss reduction (R4-proven protocol).
__global__ __launch_bounds__(128, 4) void mega_kernel(
    const unsigned short* __restrict__ fb, const float* __restrict__ sq,
    int* __restrict__ an, int* __restrict__ ap,
    const float* __restrict__ logits, const int* __restrict__ tgt,
    float* __restrict__ xloss, float* __restrict__ out,
    int* __restrict__ ctrs) {
  const int b = blockIdx.x;
  const int tid = threadIdx.x;
  const int wave = tid >> 6, lane = tid & 63;

  if (b >= NU) {
    // ---------------- xent: 4 rows per block, 2 per wave ----------------
    const int r0 = (b - NU) * 4 + wave * 2;
#pragma unroll
    for (int rr = 0; rr < 2; ++rr) {
      const int row = r0 + rr;
      const float* lg = logits + (size_t)row * NCLS;
      float m = -1e30f;
      for (int j = lane; j < NCLS; j += 64) m = fmaxf(m, lg[j]);
#pragma unroll
      for (int s = 32; s >= 1; s >>= 1) m = fmaxf(m, __shfl_xor(m, s, 64));
      float se = 0.f;
      for (int j = lane; j < NCLS; j += 64) se += __expf(lg[j] - m);
      se = wave_sum(se);
      if (lane == 0) xloss[row] = -(lg[tgt[row]] - m - logf(se));
    }
  } else {
    // ---------------- gemm unit ----------------
    __shared__ __align__(16) unsigned short As[TM * BK];  // 8 KB [128][32]
    __shared__ __align__(16) unsigned short Bs[TN * BK];  // 4 KB [64][32]

    // decode u = rb*(rb+1) + cb, cb in [0, 2rb+2)
    int rb = (int)((sqrtf(4.f * (float)b + 1.f) - 1.f) * 0.5f);
    while (rb * (rb + 1) > b) --rb;
    while ((rb + 1) * (rb + 2) <= b) ++rb;
    const int cb = b - rb * (rb + 1);
    const bool band = (cb >= 2 * rb);     // cols subset of rows (diag band)
    const int i0 = rb * TM, j0 = cb * TN;

    const int quad = lane >> 4, lr = lane & 15;
    const int srow = tid >> 2;            // 0..31
    const int sc   = (tid & 3) * 8;       // 0,8,16,24 (elements)
    const int slo  = srow * BK + sc;      // LDS element offset within 32 rows

    f32x4 acc[4][4];
    const f32x4 zero = {0.f, 0.f, 0.f, 0.f};
#pragma unroll
    for (int mi = 0; mi < 4; ++mi)
#pragma unroll
      for (int ni = 0; ni < 4; ++ni) acc[mi][ni] = zero;

    const unsigned short* gA = fb + (size_t)(i0 + srow) * FDIM + sc;
    const unsigned short* gB = fb + (size_t)(j0 + srow) * FDIM + sc;

    for (int k0 = 0; k0 < FDIM; k0 += BK) {
      __syncthreads();             // previous iter's LDS reads done
#pragma unroll
      for (int q = 0; q < 4; ++q)  // A: 128 rows in 4 chunks of 32
        gld_lds16(gA + k0 + (size_t)(q * 32) * FDIM, &As[q * 32 * BK + slo]);
#pragma unroll
      for (int q = 0; q < 2; ++q)  // B: 64 rows in 2 chunks of 32
        gld_lds16(gB + k0 + (size_t)(q * 32) * FDIM, &Bs[q * 32 * BK + slo]);
      __syncthreads();             // staging visible (vmcnt drained)

      bf16x8 a[4], bfr[4];
#pragma unroll
      for (int mi = 0; mi < 4; ++mi)
        a[mi] = *(const bf16x8*)&As[(wave * 64 + mi * 16 + lr) * BK + quad * 8];
#pragma unroll
      for (int ni = 0; ni < 4; ++ni)
        bfr[ni] = *(const bf16x8*)&Bs[(ni * 16 + lr) * BK + quad * 8];
#pragma unroll
      for (int mi = 0; mi < 4; ++mi)
#pragma unroll
        for (int ni = 0; ni < 4; ++ni)
          acc[mi][ni] = __builtin_amdgcn_mfma_f32_16x16x32_bf16(
              a[mi], bfr[ni], acc[mi][ni], 0, 0, 0);
    }

    // ---- epilogue: D layout col = lane&15 (j), row = quad*4 + reg (i) ----
    float sqj[4];
#pragma unroll
    for (int ni = 0; ni < 4; ++ni) sqj[ni] = sq[j0 + ni * 16 + lr];

    if (band) {
      // cols subset of rows: contains same-group pairs; transposes of all
      // cells are covered by this unit + its sibling -> row mining only.
      float rmin[4][4], rmax[4][4];
#pragma unroll
      for (int mi = 0; mi < 4; ++mi)
#pragma unroll
        for (int rg = 0; rg < 4; ++rg) { rmin[mi][rg] = 1e30f; rmax[mi][rg] = 0.f; }
#pragma unroll
      for (int mi = 0; mi < 4; ++mi) {
#pragma unroll
        for (int rg = 0; rg < 4; ++rg) {
          const int i = i0 + wave * 64 + mi * 16 + quad * 4 + rg;
          const float si_ = sq[i];
          const int gi = i >> 2;       // targets = idx // 4
#pragma unroll
          for (int ni = 0; ni < 4; ++ni) {
            const int j = j0 + ni * 16 + lr;
            const float d2 = si_ + sqj[ni] - 2.f * acc[mi][ni][rg];
            const float dist = sqrtf(fmaxf(d2, 1e-12f));
            if ((j >> 2) == gi) rmax[mi][rg] = fmaxf(rmax[mi][rg], dist);
            else                rmin[mi][rg] = fminf(rmin[mi][rg], dist);
          }
        }
      }
#pragma unroll
      for (int m = 1; m < 16; m <<= 1)
#pragma unroll
        for (int mi = 0; mi < 4; ++mi)
#pragma unroll
          for (int rg = 0; rg < 4; ++rg) {
            rmin[mi][rg] = fminf(rmin[mi][rg], __shfl_xor(rmin[mi][rg], m, 64));
            rmax[mi][rg] = fmaxf(rmax[mi][rg], __shfl_xor(rmax[mi][rg], m, 64));
          }
      if (lr == 0) {
#pragma unroll
        for (int mi = 0; mi < 4; ++mi)
#pragma unroll
          for (int rg = 0; rg < 4; ++rg) {
            const int i = i0 + wave * 64 + mi * 16 + quad * 4 + rg;
            atomicMin(&an[i], __float_as_int(rmin[mi][rg]));
            atomicMax(&ap[i], __float_as_int(rmax[mi][rg]));
          }
      }
    } else {
      // strictly-lower: all cross-group (group boundaries 4-aligned, tiles
      // 64-aligned). row-min -> an[i]; col-min (symmetry) -> an[j].
      float rmin[4][4];
      float cmin[4] = {1e30f, 1e30f, 1e30f, 1e30f};
#pragma unroll
      for (int mi = 0; mi < 4; ++mi)
#pragma unroll
        for (int rg = 0; rg < 4; ++rg) rmin[mi][rg] = 1e30f;
#pragma unroll
      for (int mi = 0; mi < 4; ++mi) {
#pragma unroll
        for (int rg = 0; rg < 4; ++rg) {
          const float si_ = sq[i0 + wave * 64 + mi * 16 + quad * 4 + rg];
#pragma unroll
          for (int ni = 0; ni < 4; ++ni) {
            const float d2 = si_ + sqj[ni] - 2.f * acc[mi][ni][rg];
            const float dist = sqrtf(fmaxf(d2, 1e-12f));
            rmin[mi][rg] = fminf(rmin[mi][rg], dist);
            cmin[ni] = fminf(cmin[ni], dist);
          }
        }
      }
#pragma unroll
      for (int m = 1; m < 16; m <<= 1)
#pragma unroll
        for (int mi = 0; mi < 4; ++mi)
#pragma unroll
          for (int rg = 0; rg < 4; ++rg)
            rmin[mi][rg] = fminf(rmin[mi][rg], __shfl_xor(rmin[mi][rg], m, 64));
      if (lr == 0) {
#pragma unroll
        for (int mi = 0; mi < 4; ++mi)
#pragma unroll
          for (int rg = 0; rg < 4; ++rg) {
            const int i = i0 + wave * 64 + mi * 16 + quad * 4 + rg;
            atomicMin(&an[i], __float_as_int(rmin[mi][rg]));
          }
      }
      // cols: reduce over quad (masks 16,32); one atomic per col per wave
#pragma unroll
      for (int ni = 0; ni < 4; ++ni) {
        cmin[ni] = fminf(cmin[ni], __shfl_xor(cmin[ni], 16, 64));
        cmin[ni] = fminf(cmin[ni], __shfl_xor(cmin[ni], 32, 64));
      }
      if (quad == 0) {
#pragma unroll
        for (int ni = 0; ni < 4; ++ni)
          atomicMin(&an[j0 + ni * 16 + lr], __float_as_int(cmin[ni]));
      }
    }
  }

  // ---------------- done protocol + fused final reduction ----------------
  __shared__ int s_last;
  __threadfence();                 // publish this block's results (release)
  __syncthreads();
  if (tid == 0) s_last = (atomicAdd(&ctrs[1], 1) == NTOT - 1) ? 1 : 0;
  __syncthreads();
  if (s_last) {
    __threadfence();               // acquire
    float st = 0.f, sx = 0.f;
    for (int i = tid; i < BATCH; i += 128) {
      const float a = __int_as_float(__hip_atomic_load(
          &ap[i], __ATOMIC_RELAXED, __HIP_MEMORY_SCOPE_AGENT));
      const float bn = __int_as_float(__hip_atomic_load(
          &an[i], __ATOMIC_RELAXED, __HIP_MEMORY_SCOPE_AGENT));
      st += fmaxf(a - bn + MARGIN, 0.f);
      sx += xloss[i];
    }
    st = wave_sum(st);
    sx = wave_sum(sx);
    __shared__ float s1[2], s2[2];
    if (lane == 0) { s1[wave] = st; s2[wave] = sx; }
    __syncthreads();
    if (tid == 0)
      out[0] = (s1[0] + s1[1] + s2[0] + s2[1]) / (float)BATCH;  // ALPHA=BETA=1
  }
}

// ---------------- launch ----------------
extern "C" void kernel_launch(void* const* d_in, const int* in_sizes, int n_in,
                              void* d_out, int out_size, void* d_ws, size_t ws_size,
                              hipStream_t stream) {
  const float* logits = (const float*)d_in[0];
  const float* feat   = (const float*)d_in[1];
  const int*   tgt    = (const int*)d_in[2];
  float* out = (float*)d_out;

  // ws layout: bf16 feat copy (16 MB) | sq | an | ap | xloss | ctrs
  char* ws = (char*)d_ws;
  unsigned short* fb = (unsigned short*)ws;
  size_t off = (size_t)BATCH * FDIM * sizeof(unsigned short);
  float* sq    = (float*)(ws + off);  off += BATCH * sizeof(float);
  int*   an    = (int*)(ws + off);    off += BATCH * sizeof(int);
  int*   ap    = (int*)(ws + off);    off += BATCH * sizeof(int);
  float* xloss = (float*)(ws + off);  off += BATCH * sizeof(float);
  int*   ctrs  = (int*)(ws + off);

  prep_kernel<<<BATCH / 8, 256, 0, stream>>>(feat, fb, sq, an, ap, ctrs);
  mega_kernel<<<NTOT, 128, 0, stream>>>(fb, sq, an, ap, logits, tgt, xloss,
                                        out, ctrs);
}

// Round 8
// 209.959 us; speedup vs baseline: 1.3942x; 1.2511x over previous
//
#include <hip/hip_runtime.h>
#include <hip/hip_bf16.h>

// Problem constants (from reference)
constexpr int BATCH = 4096;   // N
constexpr int NCLS  = 751;    // classes
constexpr int FDIM  = 2048;   // D
constexpr int TILE  = 128;    // C-tile (square)
constexpr int BK    = 64;     // K-step per LDS buffer (2 mfma k-steps of 32)
constexpr int NIT   = FDIM / BK;  // 32 iterations
constexpr float MARGIN = 0.5f;

constexpr int NTILE = BATCH / TILE;               // 32
constexpr int NOFF  = NTILE * (NTILE - 1) / 2;    // 496 strictly-lower tiles
constexpr int NGEMM = NOFF + NTILE;               // 528 (diag last = light surplus)
constexpr int NXT   = 256;                        // xent tickets, 16 rows each
constexpr int NTICK = NGEMM + NXT;                // 784
constexpr int NWORKERS = 512;                     // 2 blocks/CU, persistent

typedef __attribute__((ext_vector_type(8))) short bf16x8;  // 8 bf16 = 4 VGPRs
typedef __attribute__((ext_vector_type(4))) float f32x4;

// ---------------- helpers ----------------
__device__ __forceinline__ float wave_sum(float v) {
#pragma unroll
  for (int m = 32; m >= 1; m >>= 1) v += __shfl_xor(v, m, 64);
  return v;
}

__device__ __forceinline__ unsigned short bf_bits(float x) {
  unsigned u = __float_as_uint(x);
  u += 0x7FFFu + ((u >> 16) & 1u);   // RNE to bf16
  return (unsigned short)(u >> 16);
}

__device__ __forceinline__ void gld_lds16(const void* g, void* l) {
  __builtin_amdgcn_global_load_lds(
      (const __attribute__((address_space(1))) void*)g,
      (__attribute__((address_space(3))) void*)l, 16, 0, 0);
}

// ---------------- kernel 1 (prep): fp32->bf16 convert + sumsq + init --------
__global__ __launch_bounds__(256) void prep_kernel(
    const float* __restrict__ feat, unsigned short* __restrict__ fb,
    float* __restrict__ sq, int* __restrict__ an, int* __restrict__ ap,
    int* __restrict__ ctrs) {
  const int b = blockIdx.x;
  const int tid = threadIdx.x;
  const int wave = tid >> 6, lane = tid & 63;

  if (b == 0 && tid == 0) { ctrs[0] = 0; ctrs[1] = 0; }
  if (tid < 8) {
    an[b * 8 + tid] = 0x7F000000;   // big positive float bits (min identity)
    ap[b * 8 + tid] = 0;            // 0.0f bits (max identity; dist >= 0)
  }
#pragma unroll
  for (int rr = 0; rr < 2; ++rr) {
    const int row = b * 8 + wave * 2 + rr;
    const float4* src = (const float4*)(feat + (size_t)row * FDIM);
    ushort4* dst = (ushort4*)(fb + (size_t)row * FDIM);
    float s = 0.f;
#pragma unroll
    for (int it = 0; it < 8; ++it) {     // 512 float4 per row / 64 lanes
      const int idx = it * 64 + lane;
      float4 v = src[idx];
      s += v.x * v.x + v.y * v.y + v.z * v.z + v.w * v.w;
      ushort4 o;
      o.x = bf_bits(v.x); o.y = bf_bits(v.y);
      o.z = bf_bits(v.z); o.w = bf_bits(v.w);
      dst[idx] = o;
    }
    s = wave_sum(s);
    if (lane == 0) sq[row] = s;
  }
}

// ---------------- kernel 2 (mega): persistent ticket workers ----------------
// 512 workers x 256 thr (4 waves, 2x2 grid, 4x4 frags). Tickets:
//   [0, NOFF)        strictly-lower 128x128 tiles (row+col mining)
//   [NOFF, NGEMM)    diagonal tiles (half staging, row mining, group max)
//   [NGEMM, NTICK)   xent units, 16 rows each
// BK=64: 32 iterations, 32 MFMA/wave/iter -> fixed barrier cost amortized 2x
// vs BK=32. Single-buffered 32 KB LDS (dbuf measured neutral, m99/R3).
// Dynamically-last worker does the final loss reduction (R4-proven).
__global__ __launch_bounds__(256, 2) void mega_kernel(
    const unsigned short* __restrict__ fb, const float* __restrict__ sq,
    int* __restrict__ an, int* __restrict__ ap,
    const float* __restrict__ logits, const int* __restrict__ tgt,
    float* __restrict__ xloss, float* __restrict__ out,
    int* __restrict__ ctrs) {
  __shared__ __align__(16) unsigned short As[TILE * BK];  // 16 KB [128][64]
  __shared__ __align__(16) unsigned short Bs[TILE * BK];  // 16 KB
  __shared__ int s_tile;
  __shared__ int s_last;

  const int tid = threadIdx.x;
  const int wave = tid >> 6, lane = tid & 63;
  const int wm = wave >> 1, wn = wave & 1;        // 2x2 wave grid
  const int quad = lane >> 4, lr = lane & 15;

  // staging map: issue q stages 32 rows x 128B; thread t -> row t>>3, col (t&7)*8
  const int srow = tid >> 3;           // 0..31
  const int scol = (tid & 7) * 8;      // 0..56 (elements)
  const int slo  = tid * 8;            // LDS element offset within a 4 KB chunk

  for (;;) {
    if (tid == 0) s_tile = atomicAdd(&ctrs[0], 1);
    __syncthreads();                   // write-before-barrier, read-after
    const int t = s_tile;
    if (t >= NTICK) break;

    if (t >= NGEMM) {
      // ---------------- xent unit: 16 rows, 4 per wave ----------------
      const int r0 = (t - NGEMM) * 16 + wave * 4;
#pragma unroll
      for (int rr = 0; rr < 4; ++rr) {
        const int row = r0 + rr;
        const float* lg = logits + (size_t)row * NCLS;
        float m = -1e30f;
        for (int j = lane; j < NCLS; j += 64) m = fmaxf(m, lg[j]);
#pragma unroll
        for (int s = 32; s >= 1; s >>= 1) m = fmaxf(m, __shfl_xor(m, s, 64));
        float se = 0.f;
        for (int j = lane; j < NCLS; j += 64) se += __expf(lg[j] - m);
        se = wave_sum(se);
        if (lane == 0) xloss[row] = -(lg[tgt[row]] - m - logf(se));
      }
      continue;
    }

    // ---------------- gemm tile ----------------
    int bi, bj;
    bool diag;
    if (t < NOFF) {   // strictly-lower: t = bi*(bi-1)/2 + bj, bj < bi
      bi = (int)((1.f + sqrtf(8.f * (float)t + 1.f)) * 0.5f);
      while (bi * (bi - 1) / 2 > t) --bi;
      while ((bi + 1) * bi / 2 <= t) ++bi;
      bj = t - bi * (bi - 1) / 2;
      diag = false;
    } else {
      bi = bj = t - NOFF;
      diag = true;
    }
    const int i0 = bi * TILE, j0 = bj * TILE;

    f32x4 acc[4][4];
    const f32x4 zero = {0.f, 0.f, 0.f, 0.f};
#pragma unroll
    for (int mi = 0; mi < 4; ++mi)
#pragma unroll
      for (int ni = 0; ni < 4; ++ni) acc[mi][ni] = zero;

    const unsigned short* gA = fb + (size_t)(i0 + srow) * FDIM + scol;
    const unsigned short* gB = fb + (size_t)(j0 + srow) * FDIM + scol;
    const unsigned short* Bsrc = diag ? As : Bs;

    for (int k0 = 0; k0 < FDIM; k0 += BK) {
      __syncthreads();               // previous iter's LDS reads done
#pragma unroll
      for (int q = 0; q < 4; ++q)    // A: 128 rows in 4 chunks of 32
        gld_lds16(gA + k0 + (size_t)(q * 32) * FDIM, &As[q * 2048 + slo]);
      if (!diag) {
#pragma unroll
        for (int q = 0; q < 4; ++q)
          gld_lds16(gB + k0 + (size_t)(q * 32) * FDIM, &Bs[q * 2048 + slo]);
      }
      __syncthreads();               // staging visible (vmcnt drained)

#pragma unroll
      for (int s = 0; s < 2; ++s) {  // two mfma k-steps per buffer
        bf16x8 a[4], bfr[4];
#pragma unroll
        for (int mi = 0; mi < 4; ++mi)
          a[mi] = *(const bf16x8*)
              &As[(wm * 64 + mi * 16 + lr) * BK + s * 32 + quad * 8];
#pragma unroll
        for (int ni = 0; ni < 4; ++ni)
          bfr[ni] = *(const bf16x8*)
              &Bsrc[(wn * 64 + ni * 16 + lr) * BK + s * 32 + quad * 8];
#pragma unroll
        for (int mi = 0; mi < 4; ++mi)
#pragma unroll
          for (int ni = 0; ni < 4; ++ni)
            acc[mi][ni] = __builtin_amdgcn_mfma_f32_16x16x32_bf16(
                a[mi], bfr[ni], acc[mi][ni], 0, 0, 0);
      }
    }

    // ---- epilogue: D layout col = lane&15 (j), row = quad*4 + reg (i) ----
    float sqj[4];
#pragma unroll
    for (int ni = 0; ni < 4; ++ni) sqj[ni] = sq[j0 + wn * 64 + ni * 16 + lr];

    if (diag) {
      float rmin[4][4], rmax[4][4];
#pragma unroll
      for (int mi = 0; mi < 4; ++mi)
#pragma unroll
        for (int rg = 0; rg < 4; ++rg) { rmin[mi][rg] = 1e30f; rmax[mi][rg] = 0.f; }
#pragma unroll
      for (int mi = 0; mi < 4; ++mi) {
#pragma unroll
        for (int rg = 0; rg < 4; ++rg) {
          const int i = i0 + wm * 64 + mi * 16 + quad * 4 + rg;
          const float si_ = sq[i];
          const int gi = i >> 2;       // targets = idx // 4
#pragma unroll
          for (int ni = 0; ni < 4; ++ni) {
            const int j = j0 + wn * 64 + ni * 16 + lr;
            const float d2 = si_ + sqj[ni] - 2.f * acc[mi][ni][rg];
            const float dist = sqrtf(fmaxf(d2, 1e-12f));
            if ((j >> 2) == gi) rmax[mi][rg] = fmaxf(rmax[mi][rg], dist);
            else                rmin[mi][rg] = fminf(rmin[mi][rg], dist);
          }
        }
      }
#pragma unroll
      for (int m = 1; m < 16; m <<= 1)
#pragma unroll
        for (int mi = 0; mi < 4; ++mi)
#pragma unroll
          for (int rg = 0; rg < 4; ++rg) {
            rmin[mi][rg] = fminf(rmin[mi][rg], __shfl_xor(rmin[mi][rg], m, 64));
            rmax[mi][rg] = fmaxf(rmax[mi][rg], __shfl_xor(rmax[mi][rg], m, 64));
          }
      if (lr == 0) {
#pragma unroll
        for (int mi = 0; mi < 4; ++mi)
#pragma unroll
          for (int rg = 0; rg < 4; ++rg) {
            const int i = i0 + wm * 64 + mi * 16 + quad * 4 + rg;
            atomicMin(&an[i], __float_as_int(rmin[mi][rg]));
            atomicMax(&ap[i], __float_as_int(rmax[mi][rg]));
          }
      }
    } else {
      float rmin[4][4];
      float cmin[4] = {1e30f, 1e30f, 1e30f, 1e30f};
#pragma unroll
      for (int mi = 0; mi < 4; ++mi)
#pragma unroll
        for (int rg = 0; rg < 4; ++rg) rmin[mi][rg] = 1e30f;
#pragma unroll
      for (int mi = 0; mi < 4; ++mi) {
#pragma unroll
        for (int rg = 0; rg < 4; ++rg) {
          const float si_ = sq[i0 + wm * 64 + mi * 16 + quad * 4 + rg];
#pragma unroll
          for (int ni = 0; ni < 4; ++ni) {
            const float d2 = si_ + sqj[ni] - 2.f * acc[mi][ni][rg];
            const float dist = sqrtf(fmaxf(d2, 1e-12f));
            rmin[mi][rg] = fminf(rmin[mi][rg], dist);
            cmin[ni] = fminf(cmin[ni], dist);
          }
        }
      }
#pragma unroll
      for (int m = 1; m < 16; m <<= 1)
#pragma unroll
        for (int mi = 0; mi < 4; ++mi)
#pragma unroll
          for (int rg = 0; rg < 4; ++rg)
            rmin[mi][rg] = fminf(rmin[mi][rg], __shfl_xor(rmin[mi][rg], m, 64));
      if (lr == 0) {
#pragma unroll
        for (int mi = 0; mi < 4; ++mi)
#pragma unroll
          for (int rg = 0; rg < 4; ++rg) {
            const int i = i0 + wm * 64 + mi * 16 + quad * 4 + rg;
            atomicMin(&an[i], __float_as_int(rmin[mi][rg]));
          }
      }
      // cols: reduce over quad (masks 16,32); symmetry -> an[j]
#pragma unroll
      for (int ni = 0; ni < 4; ++ni) {
        cmin[ni] = fminf(cmin[ni], __shfl_xor(cmin[ni], 16, 64));
        cmin[ni] = fminf(cmin[ni], __shfl_xor(cmin[ni], 32, 64));
      }
      if (quad == 0) {
#pragma unroll
        for (int ni = 0; ni < 4; ++ni)
          atomicMin(&an[j0 + wn * 64 + ni * 16 + lr], __float_as_int(cmin[ni]));
      }
    }
  }

  // ---------------- done protocol + fused final reduction ----------------
  __threadfence();                 // publish this block's results (release)
  __syncthreads();
  if (tid == 0) s_last = (atomicAdd(&ctrs[1], 1) == NWORKERS - 1) ? 1 : 0;
  __syncthreads();
  if (s_last) {
    __threadfence();               // acquire
    float st = 0.f, sx = 0.f;
    for (int i = tid; i < BATCH; i += 256) {
      const float a = __int_as_float(__hip_atomic_load(
          &ap[i], __ATOMIC_RELAXED, __HIP_MEMORY_SCOPE_AGENT));
      const float bn = __int_as_float(__hip_atomic_load(
          &an[i], __ATOMIC_RELAXED, __HIP_MEMORY_SCOPE_AGENT));
      st += fmaxf(a - bn + MARGIN, 0.f);
      sx += xloss[i];
    }
    st = wave_sum(st);
    sx = wave_sum(sx);
    __shared__ float s1[4], s2[4];
    if (lane == 0) { s1[wave] = st; s2[wave] = sx; }
    __syncthreads();
    if (tid == 0) {
      const float trip = (s1[0] + s1[1] + s1[2] + s1[3]) / (float)BATCH;
      const float xent = (s2[0] + s2[1] + s2[2] + s2[3]) / (float)BATCH;
      out[0] = xent + trip;  // ALPHA=BETA=1
    }
  }
}

// ---------------- launch ----------------
extern "C" void kernel_launch(void* const* d_in, const int* in_sizes, int n_in,
                              void* d_out, int out_size, void* d_ws, size_t ws_size,
                              hipStream_t stream) {
  const float* logits = (const float*)d_in[0];
  const float* feat   = (const float*)d_in[1];
  const int*   tgt    = (const int*)d_in[2];
  float* out = (float*)d_out;

  // ws layout: bf16 feat copy (16 MB) | sq | an | ap | xloss | ctrs
  char* ws = (char*)d_ws;
  unsigned short* fb = (unsigned short*)ws;
  size_t off = (size_t)BATCH * FDIM * sizeof(unsigned short);
  float* sq    = (float*)(ws + off);  off += BATCH * sizeof(float);
  int*   an    = (int*)(ws + off);    off += BATCH * sizeof(int);
  int*   ap    = (int*)(ws + off);    off += BATCH * sizeof(int);
  float* xloss = (float*)(ws + off);  off += BATCH * sizeof(float);
  int*   ctrs  = (int*)(ws + off);

  prep_kernel<<<BATCH / 8, 256, 0, stream>>>(feat, fb, sq, an, ap, ctrs);
  mega_kernel<<<NWORKERS, 256, 0, stream>>>(fb, sq, an, ap, logits, tgt, xloss,
                                            out, ctrs);
}